// Round 3
// baseline (599.485 us; speedup 1.0000x reference)
//
#include <hip/hip_runtime.h>
#include <math.h>

#define B_   8
#define N_   1024
#define T_   16
#define E_   512
#define H_   8
#define DH_  64
#define KNN_ 16

// ---------------------------------------------------------------------------
// Kernel 1: KNN over positions + log_w computation.
// One block per node i. Distances via the reference's exact formula
// (x2_i + x2_j - 2*dot, clip, sqrt(+1e-9)); diag = inf.
// 16 iterative argmin passes (ties -> lower index, like lax.top_k).
// ---------------------------------------------------------------------------
__global__ __launch_bounds__(256) void knn_kernel(const float* __restrict__ pos,
                                                  const float* __restrict__ tau_p,
                                                  int* __restrict__ knn_idx,
                                                  float* __restrict__ logw) {
    __shared__ float dist[N_];
    __shared__ float rval[4];
    __shared__ int   ridx[4];
    __shared__ float sel_d[KNN_];
    __shared__ int   sel_i[KNN_];

    const int i = blockIdx.x;
    const int t = threadIdx.x;

    const float px = pos[2 * i], py = pos[2 * i + 1];
    const float xi2 = px * px + py * py;

    for (int j = t; j < N_; j += 256) {
        const float qx = pos[2 * j], qy = pos[2 * j + 1];
        const float xj2 = qx * qx + qy * qy;
        float d2 = xi2 + xj2 - 2.0f * (px * qx + py * qy);
        d2 = fmaxf(d2, 0.0f);
        const float d = sqrtf(d2 + 1e-9f);
        dist[j] = (j == i) ? __builtin_inff() : d;
    }
    __syncthreads();

    for (int k = 0; k < KNN_; ++k) {
        float best = __builtin_inff();
        int bi = 0x7fffffff;
        for (int j = t; j < N_; j += 256) {
            const float d = dist[j];
            if (d < best) { best = d; bi = j; }   // ascending j: lowest idx kept on ties
        }
        for (int off = 32; off >= 1; off >>= 1) {
            const float ov = __shfl_down(best, off);
            const int   oi = __shfl_down(bi, off);
            if (ov < best || (ov == best && oi < bi)) { best = ov; bi = oi; }
        }
        const int wave = t >> 6;
        if ((t & 63) == 0) { rval[wave] = best; ridx[wave] = bi; }
        __syncthreads();
        if (t == 0) {
            for (int w = 1; w < 4; ++w) {
                if (rval[w] < best || (rval[w] == best && ridx[w] < bi)) { best = rval[w]; bi = ridx[w]; }
            }
            sel_d[k] = best;
            sel_i[k] = bi;
            dist[bi] = __builtin_inff();
        }
        __syncthreads();
    }

    if (t < KNN_) {
        float mean = 0.0f;
        for (int k = 0; k < KNN_; ++k) mean += sel_d[k];
        mean *= (1.0f / KNN_);
        const float scale = fmaxf(mean, 1.1920929e-7f);   // finfo(f32).eps
        const float tau_safe = fmaxf(tau_p[0], 1e-4f);    // TAU_MIN
        float lw = -(sel_d[t] / scale) / tau_safe;        // BIAS_SCALE = 1
        lw = fminf(fmaxf(lw, -10.0f), 0.0f);
        logw[i * KNN_ + t]    = lw;
        knn_idx[i * KNN_ + t] = sel_i[t];
    }
}

// ---------------------------------------------------------------------------
// Kernel 2: h_last = hidden[:,:,-1,:], neigh_mean = mean(hidden[:,:,-4:,:]).
// float4-vectorized; reads 64MB, writes 32MB.
// ---------------------------------------------------------------------------
__global__ __launch_bounds__(256) void last_mean_kernel(const float* __restrict__ hidden,
                                                        float* __restrict__ h_last,
                                                        float* __restrict__ neigh_mean) {
    const int idx = blockIdx.x * 256 + threadIdx.x;   // float4 index, total B*N*E/4
    const int e4 = idx & (E_ / 4 - 1);                // 0..127
    const int bn = idx >> 7;
    const float4* h = (const float4*)hidden;
    const size_t base = (size_t)bn * (T_ * (E_ / 4)) + e4;
    const float4 a = h[base + 12 * (E_ / 4)];
    const float4 b = h[base + 13 * (E_ / 4)];
    const float4 c = h[base + 14 * (E_ / 4)];
    const float4 d = h[base + 15 * (E_ / 4)];
    ((float4*)h_last)[idx] = d;
    float4 m;
    m.x = (a.x + b.x + c.x + d.x) * 0.25f;
    m.y = (a.y + b.y + c.y + d.y) * 0.25f;
    m.z = (a.z + b.z + c.z + d.z) * 0.25f;
    m.w = (a.w + b.w + c.w + d.w) * 0.25f;
    ((float4*)neigh_mean)[idx] = m;
}

// ---------------------------------------------------------------------------
// fp32 GEMM body: C[m][j] = sum_k A[m][k] * W[j][k] + bias[j]
// M x 512 @ (512x512)^T. 128x128 block tile, BK=16, 8x8 micro-tile per
// thread (256 threads = 16x16). k-major LDS rows padded to 132 floats:
// keeps row starts 16B-aligned for ds_read_b128; scatter-writes 2-way (free).
// Per k-step: 4 ds_read_b128 (~62cy incl. 4-way on B reads) vs 64 FMA
// (128cy) -> VALU-bound, ~70-75% FMA issue fraction. LDS 16.9KB, ~115 VGPR.
// ---------------------------------------------------------------------------
__device__ __forceinline__ void gemm_nt_128x128(const float* __restrict__ A,
                                                const float* __restrict__ W,
                                                const float* __restrict__ bias,
                                                float* __restrict__ C) {
    __shared__ float As[16][132];
    __shared__ float Ws[16][132];

    const int t  = threadIdx.x;
    const int m0 = blockIdx.x * 128;
    const int j0 = blockIdx.y * 128;

    // staging: thread t loads row (t>>1), cols (t&1)*8 .. +7 of the k-chunk
    const int srow = t >> 1;            // 0..127
    const int scol = (t & 1) * 8;       // 0 or 8
    const float* pA = A + (size_t)(m0 + srow) * 512 + scol;
    const float* pW = W + (size_t)(j0 + srow) * 512 + scol;

    // compute: 16x16 thread grid, 8x8 micro-tile
    const int tx = t & 15;              // n-group
    const int ty = t >> 4;              // m-group
    const int nb = tx * 8;
    const int mb = ty * 8;

    float acc[8][8] = {};

    for (int kc = 0; kc < 512; kc += 16) {
        const float4 a0 = *(const float4*)(pA + kc);
        const float4 a1 = *(const float4*)(pA + kc + 4);
        const float4 w0 = *(const float4*)(pW + kc);
        const float4 w1 = *(const float4*)(pW + kc + 4);
        __syncthreads();   // protect previous iteration's LDS reads
        As[scol + 0][srow] = a0.x; As[scol + 1][srow] = a0.y;
        As[scol + 2][srow] = a0.z; As[scol + 3][srow] = a0.w;
        As[scol + 4][srow] = a1.x; As[scol + 5][srow] = a1.y;
        As[scol + 6][srow] = a1.z; As[scol + 7][srow] = a1.w;
        Ws[scol + 0][srow] = w0.x; Ws[scol + 1][srow] = w0.y;
        Ws[scol + 2][srow] = w0.z; Ws[scol + 3][srow] = w0.w;
        Ws[scol + 4][srow] = w1.x; Ws[scol + 5][srow] = w1.y;
        Ws[scol + 6][srow] = w1.z; Ws[scol + 7][srow] = w1.w;
        __syncthreads();
#pragma unroll
        for (int kk = 0; kk < 16; ++kk) {
            const float4 av0 = *(const float4*)&As[kk][mb];
            const float4 av1 = *(const float4*)&As[kk][mb + 4];
            const float4 wv0 = *(const float4*)&Ws[kk][nb];
            const float4 wv1 = *(const float4*)&Ws[kk][nb + 4];
            const float a_[8] = {av0.x, av0.y, av0.z, av0.w, av1.x, av1.y, av1.z, av1.w};
            const float w_[8] = {wv0.x, wv0.y, wv0.z, wv0.w, wv1.x, wv1.y, wv1.z, wv1.w};
#pragma unroll
            for (int p = 0; p < 8; ++p)
#pragma unroll
                for (int q = 0; q < 8; ++q)
                    acc[p][q] = fmaf(a_[p], w_[q], acc[p][q]);
        }
    }

    const float4 bv0 = *(const float4*)(bias + j0 + nb);
    const float4 bv1 = *(const float4*)(bias + j0 + nb + 4);
#pragma unroll
    for (int p = 0; p < 8; ++p) {
        float4 o0, o1;
        o0.x = acc[p][0] + bv0.x; o0.y = acc[p][1] + bv0.y;
        o0.z = acc[p][2] + bv0.z; o0.w = acc[p][3] + bv0.w;
        o1.x = acc[p][4] + bv1.x; o1.y = acc[p][5] + bv1.y;
        o1.z = acc[p][6] + bv1.z; o1.w = acc[p][7] + bv1.w;
        float* crow = C + (size_t)(m0 + mb + p) * 512 + j0 + nb;
        *(float4*)crow       = o0;
        *(float4*)(crow + 4) = o1;
    }
}

__global__ __launch_bounds__(256) void qkv_gemm_kernel(const float* __restrict__ h_last,
                                                       const float* __restrict__ nmean,
                                                       const float* __restrict__ Wq,
                                                       const float* __restrict__ Wk,
                                                       const float* __restrict__ Wv,
                                                       const float* __restrict__ bq,
                                                       const float* __restrict__ bk,
                                                       const float* __restrict__ bv,
                                                       float* __restrict__ Qo,
                                                       float* __restrict__ Ko,
                                                       float* __restrict__ Vo) {
    const int which = blockIdx.z;
    const float* A    = (which == 0) ? h_last : nmean;
    const float* W    = (which == 0) ? Wq : (which == 1) ? Wk : Wv;
    const float* bias = (which == 0) ? bq : (which == 1) ? bk : bv;
    float*       C    = (which == 0) ? Qo : (which == 1) ? Ko : Vo;
    gemm_nt_128x128(A, W, bias, C);
}

__global__ __launch_bounds__(256) void out_gemm_kernel(const float* __restrict__ ctx,
                                                       const float* __restrict__ Wo,
                                                       const float* __restrict__ bo,
                                                       float* __restrict__ out) {
    gemm_nt_128x128(ctx, Wo, bo, out);
}

// ---------------------------------------------------------------------------
// Kernel 4: attention. One block per (b,n). Thread t owns float2 at offset
// 2t of each 512-float row => head h = t/32, dims (t%32)*2. Gathered K/V
// rows are fully coalesced 2KB reads and L2-resident.
// ---------------------------------------------------------------------------
__global__ __launch_bounds__(256) void attn_kernel(const float* __restrict__ Q,
                                                   const float* __restrict__ Kf,
                                                   const float* __restrict__ Vf,
                                                   const int* __restrict__ knn_idx,
                                                   const float* __restrict__ logw,
                                                   float* __restrict__ ctx) {
    const int bn = blockIdx.x;
    const int n  = bn & (N_ - 1);
    const int b  = bn >> 10;
    const int t  = threadIdx.x;

    __shared__ int   idxs[KNN_];
    __shared__ float lws[KNN_];
    if (t < KNN_) {
        idxs[t] = knn_idx[n * KNN_ + t];
        lws[t]  = logw[n * KNN_ + t];
    }
    __syncthreads();

    const float2 q = ((const float2*)Q)[(size_t)bn * 256 + t];

    float logits[KNN_];
#pragma unroll
    for (int k = 0; k < KNN_; ++k) {
        const int j = idxs[k];
        const float2 kv = ((const float2*)Kf)[((size_t)(b * N_ + j)) * 256 + t];
        float d = q.x * kv.x + q.y * kv.y;
        d += __shfl_xor(d, 1);
        d += __shfl_xor(d, 2);
        d += __shfl_xor(d, 4);
        d += __shfl_xor(d, 8);
        d += __shfl_xor(d, 16);        // masks <32: stays within the 32-lane head group
        logits[k] = d * 0.125f + lws[k];   // 1/sqrt(DH=64) = 0.125
    }

    float m = -__builtin_inff();
#pragma unroll
    for (int k = 0; k < KNN_; ++k) m = fmaxf(m, logits[k]);
    float p[KNN_];
    float s = 0.0f;
#pragma unroll
    for (int k = 0; k < KNN_; ++k) { p[k] = expf(logits[k] - m); s += p[k]; }
    const float inv = 1.0f / s;

    float2 acc = make_float2(0.0f, 0.0f);
#pragma unroll
    for (int k = 0; k < KNN_; ++k) {
        const int j = idxs[k];
        const float2 vv = ((const float2*)Vf)[((size_t)(b * N_ + j)) * 256 + t];
        const float w = p[k] * inv;
        acc.x = fmaf(w, vv.x, acc.x);
        acc.y = fmaf(w, vv.y, acc.y);
    }
    ((float2*)ctx)[(size_t)bn * 256 + t] = acc;
}

// ---------------------------------------------------------------------------
extern "C" void kernel_launch(void* const* d_in, const int* in_sizes, int n_in,
                              void* d_out, int out_size, void* d_ws, size_t ws_size,
                              hipStream_t stream) {
    const float* hidden = (const float*)d_in[0];
    const float* pos    = (const float*)d_in[1];
    const float* Wq     = (const float*)d_in[2];
    const float* bq     = (const float*)d_in[3];
    const float* Wk     = (const float*)d_in[4];
    const float* bk     = (const float*)d_in[5];
    const float* Wv     = (const float*)d_in[6];
    const float* bv     = (const float*)d_in[7];
    const float* Wo     = (const float*)d_in[8];
    const float* bo     = (const float*)d_in[9];
    const float* tau    = (const float*)d_in[10];

    float* ws      = (float*)d_ws;
    const size_t SZ = (size_t)B_ * N_ * E_;   // 4,194,304 floats
    float* h_last  = ws;                      // later reused as ctx
    float* nmean   = ws + SZ;
    float* Kb      = ws + 2 * SZ;
    float* Vb      = ws + 3 * SZ;
    int*   knn_idx = (int*)(ws + 4 * SZ);
    float* logw    = ws + 4 * SZ + N_ * KNN_;
    float* Qb      = (float*)d_out;           // d_out doubles as Q scratch
    float* out     = (float*)d_out;

    knn_kernel<<<N_, 256, 0, stream>>>(pos, tau, knn_idx, logw);
    last_mean_kernel<<<(B_ * N_ * E_ / 4) / 256, 256, 0, stream>>>(hidden, h_last, nmean);

    dim3 gqkv(B_ * N_ / 128, E_ / 128, 3);
    qkv_gemm_kernel<<<gqkv, 256, 0, stream>>>(h_last, nmean, Wq, Wk, Wv, bq, bk, bv, Qb, Kb, Vb);

    attn_kernel<<<B_ * N_, 256, 0, stream>>>(Qb, Kb, Vb, knn_idx, logw, h_last /* ctx */);

    dim3 gout(B_ * N_ / 128, E_ / 128, 1);
    out_gemm_kernel<<<gout, 256, 0, stream>>>(h_last, Wo, bo, out);
}

// Round 4
// 474.264 us; speedup vs baseline: 1.2640x; 1.2640x over previous
//
#include <hip/hip_runtime.h>
#include <math.h>

#define B_   8
#define N_   1024
#define T_   16
#define E_   512
#define H_   8
#define DH_  64
#define KNN_ 16

typedef __attribute__((ext_vector_type(8))) _Float16 half8;
typedef __attribute__((ext_vector_type(4))) float    f32x4;

// ---------------------------------------------------------------------------
// Kernel 1: KNN over positions + log_w. Unchanged (verified passing R3).
// ---------------------------------------------------------------------------
__global__ __launch_bounds__(256) void knn_kernel(const float* __restrict__ pos,
                                                  const float* __restrict__ tau_p,
                                                  int* __restrict__ knn_idx,
                                                  float* __restrict__ logw) {
    __shared__ float dist[N_];
    __shared__ float rval[4];
    __shared__ int   ridx[4];
    __shared__ float sel_d[KNN_];
    __shared__ int   sel_i[KNN_];

    const int i = blockIdx.x;
    const int t = threadIdx.x;

    const float px = pos[2 * i], py = pos[2 * i + 1];
    const float xi2 = px * px + py * py;

    for (int j = t; j < N_; j += 256) {
        const float qx = pos[2 * j], qy = pos[2 * j + 1];
        const float xj2 = qx * qx + qy * qy;
        float d2 = xi2 + xj2 - 2.0f * (px * qx + py * qy);
        d2 = fmaxf(d2, 0.0f);
        const float d = sqrtf(d2 + 1e-9f);
        dist[j] = (j == i) ? __builtin_inff() : d;
    }
    __syncthreads();

    for (int k = 0; k < KNN_; ++k) {
        float best = __builtin_inff();
        int bi = 0x7fffffff;
        for (int j = t; j < N_; j += 256) {
            const float d = dist[j];
            if (d < best) { best = d; bi = j; }
        }
        for (int off = 32; off >= 1; off >>= 1) {
            const float ov = __shfl_down(best, off);
            const int   oi = __shfl_down(bi, off);
            if (ov < best || (ov == best && oi < bi)) { best = ov; bi = oi; }
        }
        const int wave = t >> 6;
        if ((t & 63) == 0) { rval[wave] = best; ridx[wave] = bi; }
        __syncthreads();
        if (t == 0) {
            for (int w = 1; w < 4; ++w) {
                if (rval[w] < best || (rval[w] == best && ridx[w] < bi)) { best = rval[w]; bi = ridx[w]; }
            }
            sel_d[k] = best;
            sel_i[k] = bi;
            dist[bi] = __builtin_inff();
        }
        __syncthreads();
    }

    if (t < KNN_) {
        float mean = 0.0f;
        for (int k = 0; k < KNN_; ++k) mean += sel_d[k];
        mean *= (1.0f / KNN_);
        const float scale = fmaxf(mean, 1.1920929e-7f);
        const float tau_safe = fmaxf(tau_p[0], 1e-4f);
        float lw = -(sel_d[t] / scale) / tau_safe;
        lw = fminf(fmaxf(lw, -10.0f), 0.0f);
        logw[i * KNN_ + t]    = lw;
        knn_idx[i * KNN_ + t] = sel_i[t];
    }
}

// ---------------------------------------------------------------------------
// Kernel 2: h_last / neigh_mean. Unchanged (verified passing R3).
// ---------------------------------------------------------------------------
__global__ __launch_bounds__(256) void last_mean_kernel(const float* __restrict__ hidden,
                                                        float* __restrict__ h_last,
                                                        float* __restrict__ neigh_mean) {
    const int idx = blockIdx.x * 256 + threadIdx.x;
    const int e4 = idx & (E_ / 4 - 1);
    const int bn = idx >> 7;
    const float4* h = (const float4*)hidden;
    const size_t base = (size_t)bn * (T_ * (E_ / 4)) + e4;
    const float4 a = h[base + 12 * (E_ / 4)];
    const float4 b = h[base + 13 * (E_ / 4)];
    const float4 c = h[base + 14 * (E_ / 4)];
    const float4 d = h[base + 15 * (E_ / 4)];
    ((float4*)h_last)[idx] = d;
    float4 m;
    m.x = (a.x + b.x + c.x + d.x) * 0.25f;
    m.y = (a.y + b.y + c.y + d.y) * 0.25f;
    m.z = (a.z + b.z + c.z + d.z) * 0.25f;
    m.w = (a.w + b.w + c.w + d.w) * 0.25f;
    ((float4*)neigh_mean)[idx] = m;
}

// ---------------------------------------------------------------------------
// Split-fp16 MFMA GEMM: C[m][n] = sum_k A[m][k]*W[n][k] + bias[n]
// Mx512 @ (512x512)^T. 128x128 tile, BK=64, 4 waves (2x2, 64x64 each).
// fp32 -> (hi,lo) fp16 split fused into staging; 3 MFMA passes
// (Ah*Wh + Ah*Wl + Al*Wh) into fp32 acc => ~22-bit mantissa, fp32-grade.
// LDS: 4 x [128][64] f16 = 64KB (2 blocks/CU). XOR swizzle (row&7)<<4 on
// byte offset, applied on BOTH store and read (involution): fragment
// ds_read_b128 spreads 8 lanes per bank-quad uniformly => no conflict tax.
// Frag layouts (guide-verified): A/B lane l holds 8 contiguous K elems at
// row/col = l&15, k = (l>>4)*8;  D[row=(l>>4)*4+q][col=l&15].
// One-iter register prefetch hides global latency under 96 MFMAs/wave/iter.
// ---------------------------------------------------------------------------
__device__ __forceinline__ void split_store(unsigned short* __restrict__ Hs,
                                            unsigned short* __restrict__ Ls,
                                            int byt, float4 v) {
    union { _Float16 h[4]; uint2 u; } Hu, Lu;
    const float* f = (const float*)&v;
#pragma unroll
    for (int j = 0; j < 4; ++j) {
        const _Float16 hh = (_Float16)f[j];
        Hu.h[j] = hh;
        Lu.h[j] = (_Float16)(f[j] - (float)hh);   // exact residual (Sterbenz)
    }
    *(uint2*)((char*)Hs + byt) = Hu.u;
    *(uint2*)((char*)Ls + byt) = Lu.u;
}

__device__ __forceinline__ void gemm_split_f16(const float* __restrict__ A,
                                               const float* __restrict__ Wt,
                                               const float* __restrict__ bias,
                                               float* __restrict__ C) {
    __shared__ unsigned short AhS[128 * 64];
    __shared__ unsigned short AlS[128 * 64];
    __shared__ unsigned short WhS[128 * 64];
    __shared__ unsigned short WlS[128 * 64];

    const int t    = threadIdx.x;
    const int m0   = blockIdx.x * 128;
    const int j0   = blockIdx.y * 128;
    const int lane = t & 63;
    const int wv   = t >> 6;
    const int wm   = wv >> 1;        // wave row  (0..1)
    const int wn   = wv & 1;         // wave col  (0..1)
    const int lr   = lane & 15;      // fragment row/col
    const int kg   = lane >> 4;      // k-group (0..3)

    float4 ra[8], rw[8];
#pragma unroll
    for (int s = 0; s < 8; ++s) {                     // prologue: kc = 0
        const int f4 = s * 256 + t;
        const int row = f4 >> 4, k4 = f4 & 15;
        ra[s] = *(const float4*)(A  + (size_t)(m0 + row) * 512 + k4 * 4);
        rw[s] = *(const float4*)(Wt + (size_t)(j0 + row) * 512 + k4 * 4);
    }

    f32x4 acc[4][4];
    const f32x4 zero = {0.0f, 0.0f, 0.0f, 0.0f};
#pragma unroll
    for (int f = 0; f < 4; ++f)
#pragma unroll
        for (int g = 0; g < 4; ++g) acc[f][g] = zero;

    for (int it = 0; it < 8; ++it) {
        __syncthreads();                              // prev compute done
#pragma unroll
        for (int s = 0; s < 8; ++s) {
            const int f4 = s * 256 + t;
            const int row = f4 >> 4, k4 = f4 & 15;
            const int byt = (row << 7) + ((k4 * 8) ^ ((row & 7) << 4));
            split_store(AhS, AlS, byt, ra[s]);
            split_store(WhS, WlS, byt, rw[s]);
        }
        __syncthreads();
        if (it < 7) {                                 // prefetch next K-chunk
            const int kc = (it + 1) * 64;
#pragma unroll
            for (int s = 0; s < 8; ++s) {
                const int f4 = s * 256 + t;
                const int row = f4 >> 4, k4 = f4 & 15;
                ra[s] = *(const float4*)(A  + (size_t)(m0 + row) * 512 + kc + k4 * 4);
                rw[s] = *(const float4*)(Wt + (size_t)(j0 + row) * 512 + kc + k4 * 4);
            }
        }
#pragma unroll
        for (int ks = 0; ks < 2; ++ks) {
            half8 ah[4], al[4], wh[4], wl[4];
#pragma unroll
            for (int f = 0; f < 4; ++f) {
                const int row = wm * 64 + f * 16 + lr;
                const int byt = (row << 7) + (((ks * 64) + (kg * 16)) ^ ((row & 7) << 4));
                ah[f] = *(const half8*)((const char*)AhS + byt);
                al[f] = *(const half8*)((const char*)AlS + byt);
            }
#pragma unroll
            for (int g = 0; g < 4; ++g) {
                const int row = wn * 64 + g * 16 + lr;
                const int byt = (row << 7) + (((ks * 64) + (kg * 16)) ^ ((row & 7) << 4));
                wh[g] = *(const half8*)((const char*)WhS + byt);
                wl[g] = *(const half8*)((const char*)WlS + byt);
            }
            // pass-outer interleave: 16 independent acc chains between reuses
#pragma unroll
            for (int f = 0; f < 4; ++f)
#pragma unroll
                for (int g = 0; g < 4; ++g)
                    acc[f][g] = __builtin_amdgcn_mfma_f32_16x16x32_f16(ah[f], wh[g], acc[f][g], 0, 0, 0);
#pragma unroll
            for (int f = 0; f < 4; ++f)
#pragma unroll
                for (int g = 0; g < 4; ++g)
                    acc[f][g] = __builtin_amdgcn_mfma_f32_16x16x32_f16(ah[f], wl[g], acc[f][g], 0, 0, 0);
#pragma unroll
            for (int f = 0; f < 4; ++f)
#pragma unroll
                for (int g = 0; g < 4; ++g)
                    acc[f][g] = __builtin_amdgcn_mfma_f32_16x16x32_f16(al[f], wh[g], acc[f][g], 0, 0, 0);
        }
    }

#pragma unroll
    for (int g = 0; g < 4; ++g) {
        const int n  = j0 + wn * 64 + g * 16 + lr;
        const float bn = bias[n];
#pragma unroll
        for (int f = 0; f < 4; ++f) {
            const int mrow = m0 + wm * 64 + f * 16 + kg * 4;
#pragma unroll
            for (int q = 0; q < 4; ++q)
                C[(size_t)(mrow + q) * 512 + n] = acc[f][g][q] + bn;
        }
    }
}

__global__ __launch_bounds__(256, 2) void qkv_gemm_kernel(const float* __restrict__ h_last,
                                                          const float* __restrict__ nmean,
                                                          const float* __restrict__ Wq,
                                                          const float* __restrict__ Wk,
                                                          const float* __restrict__ Wv,
                                                          const float* __restrict__ bq,
                                                          const float* __restrict__ bk,
                                                          const float* __restrict__ bv,
                                                          float* __restrict__ Qo,
                                                          float* __restrict__ Ko,
                                                          float* __restrict__ Vo) {
    const int which = blockIdx.z;
    const float* A    = (which == 0) ? h_last : nmean;
    const float* W    = (which == 0) ? Wq : (which == 1) ? Wk : Wv;
    const float* bias = (which == 0) ? bq : (which == 1) ? bk : bv;
    float*       C    = (which == 0) ? Qo : (which == 1) ? Ko : Vo;
    gemm_split_f16(A, W, bias, C);
}

__global__ __launch_bounds__(256, 2) void out_gemm_kernel(const float* __restrict__ ctx,
                                                          const float* __restrict__ Wo,
                                                          const float* __restrict__ bo,
                                                          float* __restrict__ out) {
    gemm_split_f16(ctx, Wo, bo, out);
}

// ---------------------------------------------------------------------------
// Kernel 4: attention. Unchanged (verified passing R3).
// ---------------------------------------------------------------------------
__global__ __launch_bounds__(256) void attn_kernel(const float* __restrict__ Q,
                                                   const float* __restrict__ Kf,
                                                   const float* __restrict__ Vf,
                                                   const int* __restrict__ knn_idx,
                                                   const float* __restrict__ logw,
                                                   float* __restrict__ ctx) {
    const int bn = blockIdx.x;
    const int n  = bn & (N_ - 1);
    const int b  = bn >> 10;
    const int t  = threadIdx.x;

    __shared__ int   idxs[KNN_];
    __shared__ float lws[KNN_];
    if (t < KNN_) {
        idxs[t] = knn_idx[n * KNN_ + t];
        lws[t]  = logw[n * KNN_ + t];
    }
    __syncthreads();

    const float2 q = ((const float2*)Q)[(size_t)bn * 256 + t];

    float logits[KNN_];
#pragma unroll
    for (int k = 0; k < KNN_; ++k) {
        const int j = idxs[k];
        const float2 kv = ((const float2*)Kf)[((size_t)(b * N_ + j)) * 256 + t];
        float d = q.x * kv.x + q.y * kv.y;
        d += __shfl_xor(d, 1);
        d += __shfl_xor(d, 2);
        d += __shfl_xor(d, 4);
        d += __shfl_xor(d, 8);
        d += __shfl_xor(d, 16);
        logits[k] = d * 0.125f + lws[k];
    }

    float m = -__builtin_inff();
#pragma unroll
    for (int k = 0; k < KNN_; ++k) m = fmaxf(m, logits[k]);
    float p[KNN_];
    float s = 0.0f;
#pragma unroll
    for (int k = 0; k < KNN_; ++k) { p[k] = expf(logits[k] - m); s += p[k]; }
    const float inv = 1.0f / s;

    float2 acc = make_float2(0.0f, 0.0f);
#pragma unroll
    for (int k = 0; k < KNN_; ++k) {
        const int j = idxs[k];
        const float2 vv = ((const float2*)Vf)[((size_t)(b * N_ + j)) * 256 + t];
        const float w = p[k] * inv;
        acc.x = fmaf(w, vv.x, acc.x);
        acc.y = fmaf(w, vv.y, acc.y);
    }
    ((float2*)ctx)[(size_t)bn * 256 + t] = acc;
}

// ---------------------------------------------------------------------------
extern "C" void kernel_launch(void* const* d_in, const int* in_sizes, int n_in,
                              void* d_out, int out_size, void* d_ws, size_t ws_size,
                              hipStream_t stream) {
    const float* hidden = (const float*)d_in[0];
    const float* pos    = (const float*)d_in[1];
    const float* Wq     = (const float*)d_in[2];
    const float* bq     = (const float*)d_in[3];
    const float* Wk     = (const float*)d_in[4];
    const float* bk     = (const float*)d_in[5];
    const float* Wv     = (const float*)d_in[6];
    const float* bv     = (const float*)d_in[7];
    const float* Wo     = (const float*)d_in[8];
    const float* bo     = (const float*)d_in[9];
    const float* tau    = (const float*)d_in[10];

    float* ws      = (float*)d_ws;
    const size_t SZ = (size_t)B_ * N_ * E_;   // 4,194,304 floats
    float* h_last  = ws;                      // later reused as ctx
    float* nmean   = ws + SZ;
    float* Kb      = ws + 2 * SZ;
    float* Vb      = ws + 3 * SZ;
    int*   knn_idx = (int*)(ws + 4 * SZ);
    float* logw    = ws + 4 * SZ + N_ * KNN_;
    float* Qb      = (float*)d_out;           // d_out doubles as Q scratch
    float* out     = (float*)d_out;

    knn_kernel<<<N_, 256, 0, stream>>>(pos, tau, knn_idx, logw);
    last_mean_kernel<<<(B_ * N_ * E_ / 4) / 256, 256, 0, stream>>>(hidden, h_last, nmean);

    dim3 gqkv(B_ * N_ / 128, E_ / 128, 3);
    qkv_gemm_kernel<<<gqkv, 256, 0, stream>>>(h_last, nmean, Wq, Wk, Wv, bq, bk, bv, Qb, Kb, Vb);

    attn_kernel<<<B_ * N_, 256, 0, stream>>>(Qb, Kb, Vb, knn_idx, logw, h_last /* ctx */);

    dim3 gout(B_ * N_ / 128, E_ / 128, 1);
    out_gemm_kernel<<<gout, 256, 0, stream>>>(h_last, Wo, bo, out);
}